// Round 1
// baseline (112.292 us; speedup 1.0000x reference)
//
#include <hip/hip_runtime.h>

// HDR+ align, 2-kernel version, round 4.
// K1: pyramid, 4x4-L3 tiles (22KB LDS, 2048 blocks) hierarchically in LDS.
// K2: quadtree block matching: 2 barriers/round, register-carried offsets,
//     redundant per-lane argmin/subpixel, 1-row/lane SSD (no spills).
// Constants: T=16, SR=4, PADD=1, SS=11, SSC=9, WIN=26, SW=0.1, GR=2, batch 4, 512x512.

#define NB 4
#define NPIX (NB * 512 * 512)

// Composite 1D tap of (normalized gaussian sigma=1 r=2) followed by avg-pool-2.
constexpr float H6[6] = {
    0.027244342f, 0.149345013f, 0.323410645f,
    0.323410645f, 0.149345013f, 0.027244342f
};

// ---------------------------------------------------------------------------
// K1: pyramid. One block = 4x4 region of L3 (covers 32x32 L0). Grid (16,16,8).
// LDS overlay (floats): patch[0..3839] s64, tmpH1[3840..5519] s28,
// l1[0..783] s28 (overlays dead patch), tmpH2[784..1119] s12,
// l2[1120..1263] s12, tmpH3[1264..1311] s4.  Total 5520 fl = 22.1 KB.
// ---------------------------------------------------------------------------
__global__ void __launch_bounds__(256, 4)
pyramid_kernel(const float* __restrict__ src, const float* __restrict__ dst,
               float* __restrict__ ws) {
    __shared__ float smem[5520];
    float* patch = smem;            // 60 rows, stride 64
    float* tmpH1 = smem + 3840;     // 60 rows, stride 28
    float* l1    = smem;            // 28 rows, stride 28
    float* tmpH2 = smem + 784;      // 28 rows, stride 12
    float* l2    = smem + 1120;     // 12 rows, stride 12
    float* tmpH3 = smem + 1264;     // 12 rows, stride 4

    float* sL1 = ws;
    float* dL1 = sL1 + 4 * 65536;
    float* sL2 = dL1 + 4 * 65536;
    float* dL2 = sL2 + 4 * 16384;
    float* sL3 = dL2 + 4 * 16384;
    float* dL3 = sL3 + 4 * 4096;

    const int bx = blockIdx.x, by = blockIdx.y, z = blockIdx.z;
    const int t = threadIdx.x;
    const float* in = (z < 4) ? (src + (size_t)z * 262144) : (dst + (size_t)(z - 4) * 262144);
    float* oL1 = ((z < 4) ? sL1 : dL1) + (size_t)(z & 3) * 65536;
    float* oL2 = ((z < 4) ? sL2 : dL2) + (size_t)(z & 3) * 16384;
    float* oL3 = ((z < 4) ? sL3 : dL3) + (size_t)(z & 3) * 4096;

    // P0: 60x60 L0 patch at (by*32-14, bx*32-14), zero OOB (conv zero-pad).
    {
        const int oy = by * 32 - 14, ox = bx * 32 - 14;
        for (int idx = t; idx < 3600; idx += 256) {
            int r = idx / 60, c = idx - r * 60;
            int gy = oy + r, gx = ox + c;
            float v = 0.f;
            if ((unsigned)gy < 512u && (unsigned)gx < 512u) v = in[gy * 512 + gx];
            patch[r * 64 + c] = v;
        }
    }
    __syncthreads();
    // P1: horizontal -> tmpH1[60][28]
    for (int idx = t; idx < 1680; idx += 256) {
        int r = idx / 28, v = idx - r * 28;
        const float* p = &patch[r * 64 + 2 * v];
        float a = 0.f;
        #pragma unroll
        for (int bq = 0; bq < 6; ++bq) a = fmaf(H6[bq], p[bq], a);
        tmpH1[r * 28 + v] = a;
    }
    __syncthreads();
    // P2: vertical -> l1[28][28]; zero if L1 coord OOB (per-level zero-pad).
    {
        const int oy = by * 16 - 6, ox = bx * 16 - 6;
        for (int idx = t; idx < 784; idx += 256) {
            int u = idx / 28, v = idx - u * 28;
            float a = 0.f;
            int y1 = oy + u, x1 = ox + v;
            if ((unsigned)y1 < 256u && (unsigned)x1 < 256u) {
                #pragma unroll
                for (int bq = 0; bq < 6; ++bq) a = fmaf(H6[bq], tmpH1[(2 * u + bq) * 28 + v], a);
            }
            l1[u * 28 + v] = a;
        }
    }
    __syncthreads();
    // P3: write canonical L1 16x16 + horizontal -> tmpH2[28][12]
    {
        int u = t >> 4, v = t & 15;
        oL1[(by * 16 + u) * 256 + bx * 16 + v] = l1[(6 + u) * 28 + 6 + v];
    }
    for (int idx = t; idx < 336; idx += 256) {
        int r = idx / 12, v = idx - r * 12;
        const float* p = &l1[r * 28 + 2 * v];
        float a = 0.f;
        #pragma unroll
        for (int bq = 0; bq < 6; ++bq) a = fmaf(H6[bq], p[bq], a);
        tmpH2[r * 12 + v] = a;
    }
    __syncthreads();
    // P4: vertical -> l2[12][12]; zero if L2 coord OOB.
    {
        const int oy = by * 8 - 2, ox = bx * 8 - 2;
        if (t < 144) {
            int u = t / 12, v = t - u * 12;
            float a = 0.f;
            int y2 = oy + u, x2 = ox + v;
            if ((unsigned)y2 < 128u && (unsigned)x2 < 128u) {
                #pragma unroll
                for (int bq = 0; bq < 6; ++bq) a = fmaf(H6[bq], tmpH2[(2 * u + bq) * 12 + v], a);
            }
            l2[u * 12 + v] = a;
        }
    }
    __syncthreads();
    // P5: write canonical L2 8x8 + horizontal -> tmpH3[12][4]
    if (t < 64) {
        int u = t >> 3, v = t & 7;
        oL2[(by * 8 + u) * 128 + bx * 8 + v] = l2[(2 + u) * 12 + 2 + v];
    } else if (t < 112) {
        int idx = t - 64;
        int r = idx >> 2, v = idx & 3;
        const float* p = &l2[r * 12 + 2 * v];
        float a = 0.f;
        #pragma unroll
        for (int bq = 0; bq < 6; ++bq) a = fmaf(H6[bq], p[bq], a);
        tmpH3[r * 4 + v] = a;
    }
    __syncthreads();
    // P6: vertical -> L3 4x4, write global.
    if (t < 16) {
        int u = t >> 2, v = t & 3;
        float a = 0.f;
        #pragma unroll
        for (int bq = 0; bq < 6; ++bq) a = fmaf(H6[bq], tmpH3[(2 * u + bq) * 4 + v], a);
        oL3[(by * 4 + u) * 64 + bx * 4 + v] = a;
    }
}

// ---------------------------------------------------------------------------
// K2 helper: one block-matching level. FULL=true: all 256 threads, 1 row/lane.
// FULL=false: a 128-thread slot, 2 rows/lane (sequential). Exactly 2 barriers.
// Result (oy, ox, od) is computed redundantly by EVERY lane (identical fp ops
// on identical LDS data -> bitwise identical) so offsets live in registers.
// ---------------------------------------------------------------------------
template<bool FULL>
__device__ __forceinline__ void do_level(const float* __restrict__ simg,
                                         const float* __restrict__ dimg, int H,
                                         int ty, int tx, float pary, float parx, bool first,
                                         float* win, float* st, float* dist, int lt,
                                         float& roy, float& rox, float& rod) {
    constexpr int NL = FULL ? 256 : 128;

    float dyf = 0.f, dxf = 0.f;
    if (!first) {
        float iy = (float)(ty * 16), ix = (float)(tx * 16);
        // _inherit: round(clip(2*par + i, 0, H-16) - i), half-to-even (rintf).
        dyf = rintf(fminf(fmaxf(2.f * pary + iy, 0.f), (float)(H - 16)) - iy);
        dxf = rintf(fminf(fmaxf(2.f * parx + ix, 0.f), (float)(H - 16)) - ix);
    }
    const int ioy = (int)dyf, iox = (int)dxf;
    const int y0 = ty * 16 + ioy - 5;
    const int x0 = tx * 16 + iox - 5;

    for (int idx = lt; idx < 676; idx += NL) {
        int r = idx / 26, c = idx - r * 26;
        int gy = min(max(y0 + r, 0), H - 1);
        int gx = min(max(x0 + c, 0), H - 1);
        win[r * 28 + c] = dimg[gy * H + gx];
    }
    if (lt < 64) {
        int r = lt >> 2, q = lt & 3;
        const float4* srow = (const float4*)(simg + (size_t)(ty * 16 + r) * H + tx * 16);
        ((float4*)&st[r * 16])[q] = srow[q];
    }
    __syncthreads();   // B1

    const int dy = FULL ? (lt >> 4) : (lt >> 3);
    if (dy < 11) {
        float acc[11];
        #pragma unroll
        for (int q = 0; q < 11; ++q) acc[q] = 0.f;
        constexpr int ROWS = FULL ? 1 : 2;
        #pragma unroll
        for (int rr = 0; rr < ROWS; ++rr) {
            const int i = FULL ? (lt & 15) : ((lt & 7) * 2 + rr);
            float w[28], s[16];
            const float4* wp = (const float4*)&win[(dy + i) * 28];
            #pragma unroll
            for (int q = 0; q < 7; ++q) ((float4*)w)[q] = wp[q];
            const float4* sp = (const float4*)&st[i * 16];
            #pragma unroll
            for (int q = 0; q < 4; ++q) ((float4*)s)[q] = sp[q];
            #pragma unroll
            for (int dx = 0; dx < 11; ++dx) {
                #pragma unroll
                for (int j = 0; j < 16; ++j) {
                    float d = w[dx + j] - s[j];
                    acc[dx] = fmaf(d, d, acc[dx]);
                }
            }
        }
        // reduce over row groups (within-wave shfl_xor)
        constexpr int MMAX = FULL ? 8 : 4;
        #pragma unroll
        for (int m = 1; m <= MMAX; m <<= 1) {
            #pragma unroll
            for (int dx = 0; dx < 11; ++dx) acc[dx] += __shfl_xor(acc[dx], m);
        }
        const bool leader = FULL ? ((lt & 15) == 0) : ((lt & 7) == 0);
        if (leader) {
            float ay = (float)(dy - 5) * (1.f / 11.f);
            #pragma unroll
            for (int dx = 0; dx < 11; ++dx) {
                float ax = (float)(dx - 5) * (1.f / 11.f);
                dist[dy * 11 + dx] = acc[dx] * (1.f / 256.f) + 0.1f * (ay * ay + ax * ax);
            }
        }
    }
    __syncthreads();   // B2

    // Redundant per-lane argmin over central 9x9 (first occurrence on ties).
    const int l = lt & 63;
    float bv; int bk;
    {
        int k = l;                                    // 0..63 < 81 always
        int py = k / 9, px = k - (k / 9) * 9;
        bv = dist[(py + 1) * 11 + (px + 1)]; bk = k;
        k = l + 64;
        if (k < 81) {
            py = k / 9; px = k - (k / 9) * 9;
            float d = dist[(py + 1) * 11 + (px + 1)];
            if (d < bv) { bv = d; bk = k; }           // strict: tie keeps smaller k
        }
    }
    #pragma unroll
    for (int m = 1; m <= 32; m <<= 1) {
        float ov = __shfl_xor(bv, m);
        int   ok = __shfl_xor(bk, m);
        if (ov < bv || (ov == bv && ok < bk)) { bv = ov; bk = ok; }
    }
    // Redundant per-lane subpixel refine (broadcast LDS reads).
    {
        int py = bk / 9, px = bk - (bk / 9) * 9;
        float y00 = dist[(py + 0) * 11 + (px + 0)], y01 = dist[(py + 0) * 11 + (px + 1)], y02 = dist[(py + 0) * 11 + (px + 2)];
        float y10 = dist[(py + 1) * 11 + (px + 0)], y11 = dist[(py + 1) * 11 + (px + 1)], y12 = dist[(py + 1) * 11 + (px + 2)];
        float y20 = dist[(py + 2) * 11 + (px + 0)], y21 = dist[(py + 2) * 11 + (px + 1)], y22 = dist[(py + 2) * 11 + (px + 2)];

        float a11 = (y00 - 2.f * y01 + y02 + 2.f * y10 - 4.f * y11 + 2.f * y12 + y20 - 2.f * y21 + y22) * 0.25f;
        a11 = fmaxf(a11, 0.f);
        float a22 = (y00 + 2.f * y01 + y02 - 2.f * y10 - 4.f * y11 - 2.f * y12 + y20 + 2.f * y21 + y22) * 0.25f;
        a22 = fmaxf(a22, 0.f);
        float a12 = (y00 - y02 - y20 + y22) * 0.25f;
        float b1  = (-y00 + y02 - 2.f * y10 + 2.f * y12 - y20 + y22) * 0.125f;
        float b2  = (-y00 - 2.f * y01 - y02 + y20 + 2.f * y21 + y22) * 0.125f;

        float det  = a11 * a22 - a12 * a12;
        float a12z = (det < 0.f) ? 0.f : a12;
        float mu_x = -(a22 * b1 - a12z * b2) / det;   // inf/nan when det==0 -> filtered
        float mu_y = -(a11 * b2 - a12z * b1) / det;
        float mu_len = sqrtf(mu_x * mu_x + mu_y * mu_y);
        float addx = (mu_len < 1.f) ? mu_x : 0.f;     // NaN -> false, matches jnp.where
        float addy = (mu_len < 1.f) ? mu_y : 0.f;

        roy = dyf + (float)(py - 4) + addy;
        rox = dxf + (float)(px - 4) + addx;
        rod = bv;
    }
}

// ---------------------------------------------------------------------------
// K2: one block per S1 tile (1024 blocks, 256 thr). Rounds: S3,S2,S1 full-width,
// then 2 rounds of 2 S0 children (128-thr slots) with fused pixel expand.
// ---------------------------------------------------------------------------
__global__ void __launch_bounds__(256, 4)
step_chain_kernel(const float* __restrict__ src, const float* __restrict__ dst,
                  const float* __restrict__ ws, float* __restrict__ out) {
    __shared__ float winS[2][26 * 28];
    __shared__ float stS[2][256];
    __shared__ float distS[2][128];

    const float* sL1 = ws;
    const float* dL1 = sL1 + 4 * 65536;
    const float* sL2 = dL1 + 4 * 65536;
    const float* dL2 = sL2 + 4 * 16384;
    const float* sL3 = dL2 + 4 * 16384;
    const float* dL3 = sL3 + 4 * 4096;

    const int gid = blockIdx.x;
    const int b   = gid >> 8;
    const int ty1 = (gid >> 4) & 15;
    const int tx1 = gid & 15;
    const int t    = threadIdx.x;
    const int slot = t >> 7;
    const int s_t  = t & 127;

    const float* s0 = src + (size_t)b * 262144; const float* d0 = dst + (size_t)b * 262144;
    const float* s1 = sL1 + (size_t)b * 65536;  const float* d1 = dL1 + (size_t)b * 65536;
    const float* s2 = sL2 + (size_t)b * 16384;  const float* d2 = dL2 + (size_t)b * 16384;
    const float* s3 = sL3 + (size_t)b * 4096;   const float* d3 = dL3 + (size_t)b * 4096;

    float oy, ox, od;
    do_level<true>(s3, d3,  64, ty1 >> 2, tx1 >> 2, 0.f, 0.f, true,
                   winS[0], stS[0], distS[0], t, oy, ox, od);
    do_level<true>(s2, d2, 128, ty1 >> 1, tx1 >> 1, oy, ox, false,
                   winS[0], stS[0], distS[0], t, oy, ox, od);
    do_level<true>(s1, d1, 256, ty1,      tx1,      oy, ox, false,
                   winS[0], stS[0], distS[0], t, oy, ox, od);
    const float s1y = oy, s1x = ox;

    #pragma unroll
    for (int half = 0; half < 2; ++half) {
        const int ty0 = 2 * ty1 + half, tx0 = 2 * tx1 + slot;
        do_level<false>(s0, d0, 512, ty0, tx0, s1y, s1x, false,
                        winS[slot], stS[slot], distS[slot], s_t, oy, ox, od);
        // Fused expand: every lane of the slot holds identical (oy,ox,od).
        int r = s_t >> 3, c = (s_t & 7) * 2;
        int pyy = ty0 * 16 + r, pxx = tx0 * 16 + c;
        size_t pi = ((size_t)(b * 512 + pyy)) * 512 + pxx;
        float2 o; o.x = oy; o.y = ox;
        ((float2*)out)[pi]     = o;
        ((float2*)out)[pi + 1] = o;
        float2 dd; dd.x = od; dd.y = od;
        *(float2*)(out + (size_t)NPIX * 2 + pi) = dd;
    }
}

extern "C" void kernel_launch(void* const* d_in, const int* in_sizes, int n_in,
                              void* d_out, int out_size, void* d_ws, size_t ws_size,
                              hipStream_t stream) {
    const float* src = (const float*)d_in[0];   // (4,1,512,512)
    const float* dst = (const float*)d_in[1];   // (4,1,512,512)
    float* out = (float*)d_out;                  // offsets (NPIX*2) ++ dist (NPIX)
    float* ws  = (float*)d_ws;                   // pyramid levels, 2.75 MB

    hipLaunchKernelGGL(pyramid_kernel, dim3(16, 16, 8), dim3(256), 0, stream, src, dst, ws);
    hipLaunchKernelGGL(step_chain_kernel, dim3(1024), dim3(256), 0, stream, src, dst, ws, out);
}